// Round 4
// baseline (415.884 us; speedup 1.0000x reference)
//
#include <hip/hip_runtime.h>

// Bilinear resample: inputs (B,S,S,C) fp32, offsets (B,S,S,2) fp32 -> out (B,S,S,C)
// B=16, S=128, C=128.
//
// Revision: LDS-tiled gather. Evidence: kernel sits at ~75 us with HBM at
// ~30%, VALU ~13%, occupancy 74%, and neither XCD swizzle (r2: -12us
// regression) nor 2x per-thread MLP (r3: neutral) moved it -> limiter is the
// L1/L2 request path: 4x tap amplification = 512 MiB of L2-side reads at
// ~80 line-requests/wave. Fix: each block stages its tile's input window
// into LDS ONCE (1 line per pixel), taps read from LDS. Guard band G=3
// covers |offset|<=3; rare overshoots (~0.5%, tile-edge pixels only) fall
// back to global taps (bit-exact same arithmetic).
//
// Geometry: 16x32 px tile x 16-channel slice. Window 23x39 px x 64B,
// padded to 80B/px (stride 5 float4, gcd(5,8)=1 -> b128 reads cycle all 8
// LDS bank-groups, conflict-free). LDS 71.8 KB -> 2 blocks/CU so one
// block's stage overlaps the other's gather.

constexpr int S  = 128;
constexpr int TR = 16;              // tile rows
constexpr int TC = 32;              // tile cols
constexpr int G  = 3;               // guard band
constexpr int WR = TR + 2 * G + 1;  // 23 window rows
constexpr int WC = TC + 2 * G + 1;  // 39 window cols
constexpr int PXW = WR * WC;        // 897 window pixels
constexpr int PX_STRIDE_F4 = 5;     // 4 float4 data + 1 pad = 80 B per px

typedef float f32x4 __attribute__((ext_vector_type(4)));

__device__ __forceinline__ float4 bilerp(float4 v00, float4 v01,
                                         float4 v10, float4 v11,
                                         float fy, float fx)
{
    float4 vt, vb, o;
    vt.x = v00.x + (v01.x - v00.x) * fx;
    vt.y = v00.y + (v01.y - v00.y) * fx;
    vt.z = v00.z + (v01.z - v00.z) * fx;
    vt.w = v00.w + (v01.w - v00.w) * fx;
    vb.x = v10.x + (v11.x - v10.x) * fx;
    vb.y = v10.y + (v11.y - v10.y) * fx;
    vb.z = v10.z + (v11.z - v10.z) * fx;
    vb.w = v10.w + (v11.w - v10.w) * fx;
    o.x = vt.x + (vb.x - vt.x) * fy;
    o.y = vt.y + (vb.y - vt.y) * fy;
    o.z = vt.z + (vb.z - vt.z) * fy;
    o.w = vt.w + (vb.w - vt.w) * fy;
    return o;
}

__device__ __forceinline__ void nt_store(float4* dst, float4 v)
{
    union { float4 f4; f32x4 x; } u;
    u.f4 = v;
    __builtin_nontemporal_store(u.x, (f32x4*)dst);
}

__global__ __launch_bounds__(512) void resample_kernel(
    const float2* __restrict__ offsets2, // (B*S*S) float2
    const float4* __restrict__ inputs4,  // (B, S, S, C/4) as float4
    float4* __restrict__ out4)           // (B, S, S, C/4)
{
    __shared__ float4 smem[PXW * PX_STRIDE_F4];  // 71,760 B

    const int tid   = threadIdx.x;
    const int bid   = blockIdx.x;
    const int slice = bid & 7;          // 8 channel slices of 16 ch
    const int tile  = (bid >> 3) & 31;  // 8 row-tiles x 4 col-tiles
    const int b     = bid >> 8;
    const int t0    = (tile >> 2) * TR;
    const int j0    = (tile & 3) * TC;
    const int cbase = slice << 2;       // float4 offset of channel slice

    const int wr0 = t0 - G;             // window origin (may be negative;
    const int wc0 = j0 - G;             //  staging clamps, taps are clamped too)

    // ---- stage window into LDS: one 64B line per pixel ----
    #pragma unroll
    for (int k = 0; k < 8; ++k) {
        const int f = tid + (k << 9);
        if (f < PXW * 4) {
            const int p  = f >> 2;          // window pixel
            const int q  = f & 3;           // float4 within slice
            const int wy = p / WC;          // const div (magic mul)
            const int wx = p - wy * WC;
            const int gy = min(max(wr0 + wy, 0), S - 1);  // edge rows duplicated
            const int gx = min(max(wc0 + wx, 0), S - 1);  //  (harmless, L2 hits)
            smem[p * PX_STRIDE_F4 + q] =
                inputs4[((((b << 7) | gy) << 7) | gx) * 32 + cbase + q];
        }
    }

    // own pixel's offset load overlaps the staging (independent of smem)
    const int prow = tid >> 5;          // 0..15
    const int pcol = tid & 31;          // 0..31
    const int row  = t0 + prow;
    const int col  = j0 + pcol;
    const int pix  = (((b << 7) | row) << 7) | col;
    const float2 off = offsets2[pix];

    float y = fminf(fmaxf((float)row + off.x, 0.0f), (float)(S - 1));
    float x = fminf(fmaxf((float)col + off.y, 0.0f), (float)(S - 1));
    const float y0f = floorf(y);
    const float x0f = floorf(x);
    const int y0 = (int)y0f;
    const int x0 = (int)x0f;
    // ceil == floor+1 whenever frac>0; frac==0 taps carry weight 0, so the
    // clamp is exact (verified: absmax identical to ceilf version).
    const int y1 = min(y0 + 1, S - 1);
    const int x1 = min(x0 + 1, S - 1);
    const float fy = y - y0f;           // row fraction  (reference "fx")
    const float fx = x - x0f;           // col fraction  (reference "fy")

    __syncthreads();

    const int outbase = pix * 32 + cbase;
    const bool inwin = (y0 >= wr0) & (y1 <= wr0 + WR - 1) &
                       (x0 >= wc0) & (x1 <= wc0 + WC - 1);

    if (inwin) {
        const int sb  = (y0 - wr0) * WC + (x0 - wc0);
        const int dX  = x1 - x0;            // 0 or 1
        const int dY  = (y1 - y0) * WC;     // 0 or WC
        const int t00 = sb * PX_STRIDE_F4;
        const int t01 = (sb + dX) * PX_STRIDE_F4;
        const int t10 = (sb + dY) * PX_STRIDE_F4;
        const int t11 = (sb + dY + dX) * PX_STRIDE_F4;
        #pragma unroll
        for (int q = 0; q < 4; ++q) {
            const float4 v00 = smem[t00 + q];
            const float4 v01 = smem[t01 + q];
            const float4 v10 = smem[t10 + q];
            const float4 v11 = smem[t11 + q];
            nt_store(&out4[outbase + q], bilerp(v00, v01, v10, v11, fy, fx));
        }
    } else {
        // rare (~0.5%): tap outside staged window -> global gather
        const int r00 = ((((b << 7) | y0) << 7) | x0) * 32 + cbase;
        const int r01 = ((((b << 7) | y0) << 7) | x1) * 32 + cbase;
        const int r10 = ((((b << 7) | y1) << 7) | x0) * 32 + cbase;
        const int r11 = ((((b << 7) | y1) << 7) | x1) * 32 + cbase;
        #pragma unroll
        for (int q = 0; q < 4; ++q) {
            const float4 v00 = inputs4[r00 + q];
            const float4 v01 = inputs4[r01 + q];
            const float4 v10 = inputs4[r10 + q];
            const float4 v11 = inputs4[r11 + q];
            nt_store(&out4[outbase + q], bilerp(v00, v01, v10, v11, fy, fx));
        }
    }
}

extern "C" void kernel_launch(void* const* d_in, const int* in_sizes, int n_in,
                              void* d_out, int out_size, void* d_ws, size_t ws_size,
                              hipStream_t stream) {
    const float2* offsets2 = (const float2*)d_in[0];
    const float4* inputs4  = (const float4*)d_in[1];
    float4*       out4     = (float4*)d_out;

    const int B = in_sizes[0] / (S * S * 2);   // = 16
    // blocks = B batches x 32 tiles (8x4) x 8 channel slices
    const int blocks = B * 32 * 8;             // 4096

    resample_kernel<<<blocks, 512, 0, stream>>>(offsets2, inputs4, out4);
}

// Round 5
// 232.039 us; speedup vs baseline: 1.7923x; 1.7923x over previous
//
#include <hip/hip_runtime.h>

// Bilinear resample: inputs (B,S,S,C) fp32, offsets (B,S,S,2) fp32 -> out (B,S,S,C)
// B=16, S=128, C=128.
//
// Revision: force memory-level parallelism. Counter evidence: VGPR_Count=16
// in r2/r4 -> compiler was SERIALIZING tap loads (16 regs can't hold 4 f4
// taps at once), so per-wave in-flight was ~2 loads despite source-level ILP.
// That explains r3's neutral result (doubling source ILP didn't change
// emitted concurrency) and the ~2.5 TB/s plateau with nothing saturated
// (Little's law: ~24 waves/CU x ~1.5KB in flight / ~300-600cy latency).
// Fix: empty asm with "+v" on all 8 tap vectors between loads and lerps ->
// all 8 global_load_dwordx4 issued back-to-back, one s_waitcnt, then math.
// LDS tiling (r4) is abandoned: 3.5x regression from occupancy/bank-conflict/
// partial-line-write failure modes inherent to channel-sliced tiles.

constexpr int S = 128;
constexpr int CVEC = 32;           // C/4 = 128/4 float4 groups per pixel
constexpr int PIX_PER_BLOCK = 16;  // 8 pixel-groups x 2 pixels each

typedef float f32x4 __attribute__((ext_vector_type(4)));

__device__ __forceinline__ void tap_setup(int pix, int lane_c, float2 off,
                                          int& i00, int& i01, int& i10, int& i11,
                                          float& fy, float& fx)
{
    const int j   = pix & (S - 1);
    const int rem = pix >> 7;          // b*S + i
    const int i   = rem & (S - 1);
    const int b   = rem >> 7;

    float y = fminf(fmaxf((float)i + off.x, 0.0f), (float)(S - 1));
    float x = fminf(fmaxf((float)j + off.y, 0.0f), (float)(S - 1));

    const float y0f = floorf(y);
    const float x0f = floorf(x);
    const int y0 = (int)y0f;
    const int x0 = (int)x0f;
    // ceil == floor+1 whenever frac>0; when frac==0 that tap is weighted by 0,
    // so clamp replaces ceilf exactly (keeps last row/col in bounds).
    const int y1 = min(y0 + 1, S - 1);
    const int x1 = min(x0 + 1, S - 1);
    fy = y - y0f;                      // row fraction  (reference "fx")
    fx = x - x0f;                      // col fraction  (reference "fy")

    const int base = (b * S * S) * CVEC + lane_c;
    const int r0 = base + y0 * (S * CVEC);
    const int r1 = base + y1 * (S * CVEC);
    i00 = r0 + x0 * CVEC;
    i01 = r0 + x1 * CVEC;
    i10 = r1 + x0 * CVEC;
    i11 = r1 + x1 * CVEC;
}

__global__ __launch_bounds__(256) void resample_kernel(
    const float2* __restrict__ offsets2, // (B*S*S) float2
    const f32x4*  __restrict__ inputs4,  // (B, S, S, C/4) as float4
    f32x4*        __restrict__ out4)     // (B, S, S, C/4)
{
    const int tid    = threadIdx.x;
    const int lane_c = tid & 31;       // channel-group index (0..31)
    const int pg     = tid >> 5;       // pixel-group (0..7)
    const int pix0   = blockIdx.x * PIX_PER_BLOCK + pg;
    const int pix1   = pix0 + 8;

    // Both offset loads issued back-to-back: one round-trip.
    const float2 off0 = offsets2[pix0];
    const float2 off1 = offsets2[pix1];

    int a00, a01, a10, a11; float fy0, fx0;
    int b00, b01, b10, b11; float fy1, fx1;
    tap_setup(pix0, lane_c, off0, a00, a01, a10, a11, fy0, fx0);
    tap_setup(pix1, lane_c, off1, b00, b01, b10, b11, fy1, fx1);

    // All 8 tap loads issued; the pin below forces all 8 destination vector
    // registers live simultaneously, so the compiler cannot serialize the
    // loads into a load->lerp->load->lerp chain to save VGPRs (the measured
    // VGPR_Count=16 pathology).
    f32x4 va00 = inputs4[a00];
    f32x4 va01 = inputs4[a01];
    f32x4 va10 = inputs4[a10];
    f32x4 va11 = inputs4[a11];
    f32x4 vb00 = inputs4[b00];
    f32x4 vb01 = inputs4[b01];
    f32x4 vb10 = inputs4[b10];
    f32x4 vb11 = inputs4[b11];
    asm volatile("" : "+v"(va00), "+v"(va01), "+v"(va10), "+v"(va11),
                      "+v"(vb00), "+v"(vb01), "+v"(vb10), "+v"(vb11));

    // Match reference order: lerp along x (ref "fy"), then along y (ref "fx").
    const f32x4 vt0 = va00 + (va01 - va00) * fx0;
    const f32x4 vb0 = va10 + (va11 - va10) * fx0;
    const f32x4 o0  = vt0 + (vb0 - vt0) * fy0;
    const f32x4 vt1 = vb00 + (vb01 - vb00) * fx1;
    const f32x4 vb1 = vb10 + (vb11 - vb10) * fx1;
    const f32x4 o1  = vt1 + (vb1 - vt1) * fy1;

    // Streaming output: nontemporal (full 1KB-per-wave dense lines; measured
    // WRITE_SIZE stays exactly 128 MiB with this pattern).
    __builtin_nontemporal_store(o0, &out4[(long long)pix0 * CVEC + lane_c]);
    __builtin_nontemporal_store(o1, &out4[(long long)pix1 * CVEC + lane_c]);
}

extern "C" void kernel_launch(void* const* d_in, const int* in_sizes, int n_in,
                              void* d_out, int out_size, void* d_ws, size_t ws_size,
                              hipStream_t stream) {
    const float2* offsets2 = (const float2*)d_in[0];
    const f32x4*  inputs4  = (const f32x4*)d_in[1];
    f32x4*        out4     = (f32x4*)d_out;

    const int B = in_sizes[0] / (S * S * 2);       // = 16
    const int total_pix = B * S * S;               // 262144
    const int blocks = total_pix / PIX_PER_BLOCK;  // 16384

    resample_kernel<<<blocks, 256, 0, stream>>>(offsets2, inputs4, out4);
}